// Round 1
// baseline (537.293 us; speedup 1.0000x reference)
//
#include <hip/hip_runtime.h>

#define B_   32
#define C_   512
#define HW   3136        // 56*56
#define KTOP 409
#define KLOW 103
#define F4   784         // HW/4

// ---------------- Kernel 1: global average pool ----------------
// one block per (b,c) channel; 784 float4 reduced by 256 threads
__global__ __launch_bounds__(256) void k_pool(const float* __restrict__ x,
                                              float* __restrict__ pooled) {
    int bc = blockIdx.x;
    const float4* src = (const float4*)(x + (size_t)bc * HW);
    int t = threadIdx.x;
    float s = 0.f;
    for (int i = t; i < F4; i += 256) {
        float4 v = src[i];
        s += (v.x + v.y) + (v.z + v.w);
    }
    for (int off = 32; off > 0; off >>= 1) s += __shfl_down(s, off, 64);
    __shared__ float part[4];
    int lane = t & 63, wv = t >> 6;
    if (lane == 0) part[wv] = s;
    __syncthreads();
    if (t == 0) {
        float tot = (part[0] + part[1]) + (part[2] + part[3]);
        pooled[bc] = tot * (1.0f / (float)HW);
    }
}

// ---------------- Kernel 2: exact top_k ranking ----------------
// one block per batch, thread c computes rank of channel c with
// jax.lax.top_k tie-break (ties -> lower index first)
__global__ __launch_bounds__(512) void k_rank(const float* __restrict__ pooled,
                                              int* __restrict__ top_src,
                                              int* __restrict__ low_src) {
    int b = blockIdx.x;
    int c = threadIdx.x;
    __shared__ float p[C_];
    p[c] = pooled[b * C_ + c];
    __syncthreads();
    float v = p[c];
    int rd = 0, ra = 0;
    for (int c2 = 0; c2 < C_; ++c2) {
        float u = p[c2];
        bool tie_lo = (u == v) && (c2 < c);
        rd += (u > v) || tie_lo;
        ra += (u < v) || tie_lo;
    }
    if (rd < KTOP) top_src[b * KTOP + rd] = c;
    if (ra < KLOW) low_src[b * KLOW + ra] = c;
}

// ---------------- Kernel 3: gather-copy top channels ----------------
// one block per (b, out-position p<409): out[b,p,:] = x[b, top_src[b][p], :]
__global__ __launch_bounds__(256) void k_topcopy(const float* __restrict__ x,
                                                 const int* __restrict__ top_src,
                                                 float* __restrict__ out) {
    int blk = blockIdx.x;                 // b*KTOP + p
    int b = blk / KTOP, pch = blk - b * KTOP;
    int src = top_src[blk];
    const float4* s = (const float4*)(x + ((size_t)b * C_ + src) * HW);
    float4*       d = (float4*)(out + ((size_t)b * C_ + pch) * HW);
    for (int i = threadIdx.x; i < F4; i += 256) d[i] = s[i];
}

// ---------------- Kernel 4: 1x1 conv fusion on low channels ----------------
// tile = 64 pixels; block = 256 threads = 64 pixels x 4 wave-uniform
// output groups of 26.  x_low tile staged in LDS; w reads are
// wave-uniform (readfirstlane) -> scalar loads.
#define PT 64
#define NT 49            // 3136 / 64
#define TO 26            // 4*26 = 104 >= 103

__global__ __launch_bounds__(256) void k_fusion(const float* __restrict__ x,
                                                const int* __restrict__ low_src,
                                                const float* __restrict__ wf,
                                                const float* __restrict__ bfv,
                                                float* __restrict__ out) {
    int blk  = blockIdx.x;               // b*NT + tile
    int b    = blk / NT, tile = blk - b * NT;
    int pix0 = tile * PT;
    __shared__ float xt[KLOW][PT];       // 26.4 KB

    const size_t xb = (size_t)b * C_ * HW;
    int t = threadIdx.x;
    // stage 103 rows x 16 float4 (coalesced 256B per row)
    for (int idx = t; idx < KLOW * (PT / 4); idx += 256) {
        int j = idx >> 4;                // row
        int q = idx & 15;                // float4 within row
        int ch = low_src[b * KLOW + j];
        float4 v = *(const float4*)(x + xb + (size_t)ch * HW + pix0 + q * 4);
        *(float4*)&xt[j][q * 4] = v;
    }
    __syncthreads();

    int p  = t & 63;
    int og = __builtin_amdgcn_readfirstlane(t >> 6);   // wave-uniform 0..3
    int o0 = og * TO;

    float acc[TO];
    const float* wr[TO];
    #pragma unroll
    for (int i = 0; i < TO; ++i) {
        int o  = o0 + i;
        int oc = (o < KLOW) ? o : (KLOW - 1);          // safe clamp for o=103
        acc[i] = bfv[oc];
        wr[i]  = wf + (size_t)oc * KLOW;
    }

    for (int j = 0; j < KLOW; ++j) {
        float xv = xt[j][p];
        #pragma unroll
        for (int i = 0; i < TO; ++i) acc[i] += wr[i][j] * xv;
    }

    float* dst = out + xb + (size_t)KTOP * HW + pix0 + p;
    #pragma unroll
    for (int i = 0; i < TO; ++i) {
        int o = o0 + i;
        if (o < KLOW) dst[(size_t)o * HW] = acc[i];
    }
}

extern "C" void kernel_launch(void* const* d_in, const int* in_sizes, int n_in,
                              void* d_out, int out_size, void* d_ws, size_t ws_size,
                              hipStream_t stream) {
    const float* x  = (const float*)d_in[0];
    const float* wf = (const float*)d_in[1];
    const float* bf = (const float*)d_in[2];
    float* out = (float*)d_out;

    float* pooled  = (float*)d_ws;                       // 16384 floats
    int*   top_src = (int*)((char*)d_ws + 16384 * 4);    // 32*409 ints
    int*   low_src = top_src + B_ * KTOP;                // 32*103 ints

    k_pool<<<B_ * C_, 256, 0, stream>>>(x, pooled);
    k_rank<<<B_, 512, 0, stream>>>(pooled, top_src, low_src);
    k_topcopy<<<B_ * KTOP, 256, 0, stream>>>(x, top_src, out);
    k_fusion<<<B_ * NT, 256, 0, stream>>>(x, low_src, wf, bf, out);
}